// Round 1
// baseline (1009.563 us; speedup 1.0000x reference)
//
#include <hip/hip_runtime.h>

#define Bv 16
#define Sv 512
#define Hv 12
#define Dv 64
#define HIDv 768

// ---------------------------------------------------------------------------
// Kernel 1: fused QKV projection.  out = X @ W^T + b, stored as [3][B][H][S][D]
// Block: 64 rows (m) x 64 cols (n), BK=16, 256 threads, 4x4 micro-tile.
// n-block == exactly one (proj, h) pair since BN=64 == D.
// ---------------------------------------------------------------------------
__global__ __launch_bounds__(256) void qkv_gemm(
    const float* __restrict__ X,
    const float* __restrict__ Wq, const float* __restrict__ Wk, const float* __restrict__ Wv,
    const float* __restrict__ bq, const float* __restrict__ bk, const float* __restrict__ bv,
    float* __restrict__ qkv)
{
    __shared__ float Xs[16][68];   // [k][m], row stride 68 floats = 272B (16B aligned)
    __shared__ float Ws[16][68];   // [k][n]

    const int t  = threadIdx.x;
    const int m0 = blockIdx.x * 64;
    const int nb = blockIdx.y;            // 0..35 : proj*12 + h
    const int proj = nb / Hv;
    const int h    = nb % Hv;
    const float* W    = (proj == 0) ? Wq : (proj == 1 ? Wk : Wv);
    const float* bias = (proj == 0) ? bq : (proj == 1 ? bk : bv);
    const int n0 = h * 64;                // row offset inside W (output feature)

    const int tm = t & 15;                // micro-tile m index (0..15)
    const int tn = t >> 4;                // micro-tile n index (0..15)
    const int lr  = t >> 2;               // staging row 0..63
    const int lk4 = (t & 3) * 4;          // staging k offset 0,4,8,12

    float acc[4][4] = {};

    for (int k0 = 0; k0 < HIDv; k0 += 16) {
        float4 xv = *(const float4*)(X + (size_t)(m0 + lr) * HIDv + k0 + lk4);
        float4 wv = *(const float4*)(W + (size_t)(n0 + lr) * HIDv + k0 + lk4);
        if (k0) __syncthreads();
        Xs[lk4 + 0][lr] = xv.x; Xs[lk4 + 1][lr] = xv.y;
        Xs[lk4 + 2][lr] = xv.z; Xs[lk4 + 3][lr] = xv.w;
        Ws[lk4 + 0][lr] = wv.x; Ws[lk4 + 1][lr] = wv.y;
        Ws[lk4 + 2][lr] = wv.z; Ws[lk4 + 3][lr] = wv.w;
        __syncthreads();
        #pragma unroll
        for (int kk = 0; kk < 16; ++kk) {
            float4 a  = *(const float4*)&Xs[kk][tm * 4];
            float4 bb = *(const float4*)&Ws[kk][tn * 4];
            acc[0][0] += a.x * bb.x; acc[0][1] += a.x * bb.y; acc[0][2] += a.x * bb.z; acc[0][3] += a.x * bb.w;
            acc[1][0] += a.y * bb.x; acc[1][1] += a.y * bb.y; acc[1][2] += a.y * bb.z; acc[1][3] += a.y * bb.w;
            acc[2][0] += a.z * bb.x; acc[2][1] += a.z * bb.y; acc[2][2] += a.z * bb.z; acc[2][3] += a.z * bb.w;
            acc[3][0] += a.w * bb.x; acc[3][1] += a.w * bb.y; acc[3][2] += a.w * bb.z; acc[3][3] += a.w * bb.w;
        }
    }

    const int b_  = m0 / Sv;
    const int s0  = m0 % Sv;
    float b0 = bias[n0 + tn * 4 + 0];
    float b1 = bias[n0 + tn * 4 + 1];
    float b2 = bias[n0 + tn * 4 + 2];
    float b3 = bias[n0 + tn * 4 + 3];
    float* obase = qkv + ((((size_t)proj * Bv + b_) * Hv + h) * Sv) * Dv;
    #pragma unroll
    for (int i = 0; i < 4; ++i) {
        float4 o = { acc[i][0] + b0, acc[i][1] + b1, acc[i][2] + b2, acc[i][3] + b3 };
        *(float4*)(obase + (size_t)(s0 + tm * 4 + i) * Dv + tn * 4) = o;
    }
}

// ---------------------------------------------------------------------------
// Kernel 2: flash-style attention with level biases + relative_key_query pos.
// Block = (b, h, 32 l-rows), 256 threads. Thread t: l = t>>3, r-slot = t&7
// (owns 8 consecutive r per 64-r chunk) and in PV phase d-range (t&7)*8..+8.
// LDS f4 slots XOR-swizzled by row bits to avoid stride-64 bank collisions.
// ---------------------------------------------------------------------------
__global__ __launch_bounds__(256) void attn(
    const float* __restrict__ qkv,
    const float* __restrict__ mask,   // [B,1,1,S]
    const int*   __restrict__ cmat,   // [B,S,S]
    const int*   __restrict__ wmat,   // [B,S,S]
    const float* __restrict__ de,     // [1023][64]
    const float* __restrict__ ce,     // [8]
    const float* __restrict__ we,     // [8]
    float* __restrict__ out)          // [B,S,768]
{
    __shared__ float qs [32][64];
    __shared__ float ks [64][64];     // K chunk, reused as V chunk in PV phase
    __shared__ float des[96][64];     // dist_emb band for this (l-block, r-chunk)
    __shared__ float Ps [32][64];     // unnormalized probs chunk
    __shared__ float tab[64];         // 0.5*ce[c] + 0.5*we[w]
    __shared__ float maskrow[Sv];

    const int t  = threadIdx.x;
    const int l0 = blockIdx.x * 32;
    const int h  = blockIdx.y;
    const int b  = blockIdx.z;

    const size_t bh = (size_t)b * Hv + h;
    const float* qp = qkv + (0 * (size_t)Bv * Hv + bh) * Sv * Dv;
    const float* kp = qkv + (1 * (size_t)Bv * Hv + bh) * Sv * Dv;
    const float* vp = qkv + (2 * (size_t)Bv * Hv + bh) * Sv * Dv;

    if (t < 64) tab[t] = 0.5f * ce[t >> 3] + 0.5f * we[t & 7];
    for (int i = t; i < Sv; i += 256) maskrow[i] = mask[(size_t)b * Sv + i];

    // stage Q tile (32 rows x 16 f4)
    #pragma unroll
    for (int i = 0; i < 2; ++i) {
        int f = t + 256 * i; int row = f >> 4; int c4 = f & 15;
        float4 v = *(const float4*)(qp + (size_t)(l0 + row) * Dv + c4 * 4);
        *(float4*)&qs[row][(c4 ^ (row & 7)) * 4] = v;
    }

    const int myl = t >> 3;     // owned l-row within tile (0..31)
    const int ms  = t & 7;      // r-slot within chunk / d-slot in PV

    const int* crow = cmat + ((size_t)b * Sv + l0 + myl) * Sv;
    const int* wrow = wmat + ((size_t)b * Sv + l0 + myl) * Sv;

    float m_run   = -1e30f;
    float run_sum = 0.f;
    float ctx[8] = {};

    for (int c = 0; c < 8; ++c) {
        const int r0 = c * 64;
        __syncthreads();                       // prev PV done before restaging
        // stage K chunk (64 rows x 16 f4)
        #pragma unroll
        for (int i = 0; i < 4; ++i) {
            int f = t + 256 * i; int row = f >> 4; int c4 = f & 15;
            float4 v = *(const float4*)(kp + (size_t)(r0 + row) * Dv + c4 * 4);
            *(float4*)&ks[row][(c4 ^ ((row >> 3) & 7)) * 4] = v;
        }
        // stage dist_emb band: rows [base, base+95]; il = 63 + myl - rl in [0,94]
        const int base = l0 - r0 + 448;
        #pragma unroll
        for (int i = 0; i < 6; ++i) {
            int f = t + 256 * i; int row = f >> 4; int c4 = f & 15;
            int g = base + row; if (g > 1022) g = 1022;   // row 95 unused
            float4 v = *(const float4*)(de + (size_t)g * Dv + c4 * 4);
            *(float4*)&des[row][(c4 ^ (row & 7)) * 4] = v;
        }
        __syncthreads();

        // scores: qk + (q+k).pe for 8 owned r's
        float acc[8] = {};
        #pragma unroll
        for (int d4 = 0; d4 < 16; ++d4) {
            float4 qv = *(const float4*)&qs[myl][(d4 ^ (myl & 7)) * 4];
            #pragma unroll
            for (int j = 0; j < 8; ++j) {
                int rl = ms * 8 + j;
                int il = 63 + myl - rl;
                float4 kv = *(const float4*)&ks[rl][(d4 ^ ((rl >> 3) & 7)) * 4];
                float4 dv = *(const float4*)&des[il][(d4 ^ (il & 7)) * 4];
                acc[j] += qv.x * kv.x + (qv.x + kv.x) * dv.x;
                acc[j] += qv.y * kv.y + (qv.y + kv.y) * dv.y;
                acc[j] += qv.z * kv.z + (qv.z + kv.z) * dv.z;
                acc[j] += qv.w * kv.w + (qv.w + kv.w) * dv.w;
            }
        }

        // level biases + scale + mask
        int4 c0 = *(const int4*)(crow + r0 + ms * 8);
        int4 c1 = *(const int4*)(crow + r0 + ms * 8 + 4);
        int4 w0 = *(const int4*)(wrow + r0 + ms * 8);
        int4 w1 = *(const int4*)(wrow + r0 + ms * 8 + 4);
        float sj[8];
        sj[0] = (acc[0] + tab[(c0.x << 3) | w0.x]) * 0.125f + maskrow[r0 + ms * 8 + 0];
        sj[1] = (acc[1] + tab[(c0.y << 3) | w0.y]) * 0.125f + maskrow[r0 + ms * 8 + 1];
        sj[2] = (acc[2] + tab[(c0.z << 3) | w0.z]) * 0.125f + maskrow[r0 + ms * 8 + 2];
        sj[3] = (acc[3] + tab[(c0.w << 3) | w0.w]) * 0.125f + maskrow[r0 + ms * 8 + 3];
        sj[4] = (acc[4] + tab[(c1.x << 3) | w1.x]) * 0.125f + maskrow[r0 + ms * 8 + 4];
        sj[5] = (acc[5] + tab[(c1.y << 3) | w1.y]) * 0.125f + maskrow[r0 + ms * 8 + 5];
        sj[6] = (acc[6] + tab[(c1.z << 3) | w1.z]) * 0.125f + maskrow[r0 + ms * 8 + 6];
        sj[7] = (acc[7] + tab[(c1.w << 3) | w1.w]) * 0.125f + maskrow[r0 + ms * 8 + 7];

        // online softmax (row = 8 lanes sharing myl)
        float cmax = sj[0];
        #pragma unroll
        for (int j = 1; j < 8; ++j) cmax = fmaxf(cmax, sj[j]);
        cmax = fmaxf(cmax, __shfl_xor(cmax, 1));
        cmax = fmaxf(cmax, __shfl_xor(cmax, 2));
        cmax = fmaxf(cmax, __shfl_xor(cmax, 4));
        float mnew = fmaxf(m_run, cmax);
        float rescale = __expf(m_run - mnew);
        float pj[8];
        float psum = 0.f;
        #pragma unroll
        for (int j = 0; j < 8; ++j) { pj[j] = __expf(sj[j] - mnew); psum += pj[j]; }
        psum += __shfl_xor(psum, 1);
        psum += __shfl_xor(psum, 2);
        psum += __shfl_xor(psum, 4);
        run_sum = run_sum * rescale + psum;
        m_run = mnew;
        #pragma unroll
        for (int i = 0; i < 8; ++i) ctx[i] *= rescale;

        __syncthreads();                       // scores done -> safe to overwrite ks/Ps
        // write unnormalized P chunk
        {
            float4 p4a = { pj[0], pj[1], pj[2], pj[3] };
            float4 p4b = { pj[4], pj[5], pj[6], pj[7] };
            *(float4*)&Ps[myl][((ms * 2 + 0) ^ (myl & 7)) * 4] = p4a;
            *(float4*)&Ps[myl][((ms * 2 + 1) ^ (myl & 7)) * 4] = p4b;
        }
        // stage V chunk over ks
        #pragma unroll
        for (int i = 0; i < 4; ++i) {
            int f = t + 256 * i; int row = f >> 4; int c4 = f & 15;
            float4 v = *(const float4*)(vp + (size_t)(r0 + row) * Dv + c4 * 4);
            *(float4*)&ks[row][(c4 ^ ((row >> 3) & 7)) * 4] = v;
        }
        __syncthreads();

        // PV: ctx[d] += P[myl][rr] * V[rr][d], d = ms*8..ms*8+7
        #pragma unroll 4
        for (int rr = 0; rr < 64; ++rr) {
            float p = Ps[myl][((rr >> 2) ^ (myl & 7)) * 4 + (rr & 3)];
            float4 v0 = *(const float4*)&ks[rr][((ms * 2 + 0) ^ ((rr >> 3) & 7)) * 4];
            float4 v1 = *(const float4*)&ks[rr][((ms * 2 + 1) ^ ((rr >> 3) & 7)) * 4];
            ctx[0] += p * v0.x; ctx[1] += p * v0.y; ctx[2] += p * v0.z; ctx[3] += p * v0.w;
            ctx[4] += p * v1.x; ctx[5] += p * v1.y; ctx[6] += p * v1.z; ctx[7] += p * v1.w;
        }
    }

    float inv = 1.0f / run_sum;
    float4 o0 = { ctx[0] * inv, ctx[1] * inv, ctx[2] * inv, ctx[3] * inv };
    float4 o1 = { ctx[4] * inv, ctx[5] * inv, ctx[6] * inv, ctx[7] * inv };
    size_t ob = ((size_t)b * Sv + l0 + myl) * HIDv + h * 64 + ms * 8;
    *(float4*)(out + ob)     = o0;
    *(float4*)(out + ob + 4) = o1;
}

extern "C" void kernel_launch(void* const* d_in, const int* in_sizes, int n_in,
                              void* d_out, int out_size, void* d_ws, size_t ws_size,
                              hipStream_t stream)
{
    const float* hs   = (const float*)d_in[0];
    const float* mask = (const float*)d_in[1];
    const int*   cmat = (const int*)  d_in[2];
    const int*   wmat = (const int*)  d_in[3];
    const float* Wq   = (const float*)d_in[4];
    const float* bq   = (const float*)d_in[5];
    const float* Wk   = (const float*)d_in[6];
    const float* bk   = (const float*)d_in[7];
    const float* Wv   = (const float*)d_in[8];
    const float* bv   = (const float*)d_in[9];
    const float* de   = (const float*)d_in[10];
    const float* ce   = (const float*)d_in[11];
    const float* we   = (const float*)d_in[12];
    float* out = (float*)d_out;
    float* qkv = (float*)d_ws;   // [3][B][H][S][D] f32 = 75.5 MB

    qkv_gemm<<<dim3(128, 36), 256, 0, stream>>>(hs, Wq, Wk, Wv, bq, bk, bv, qkv);
    attn<<<dim3(16, 12, 16), 256, 0, stream>>>(qkv, mask, cmat, wmat, de, ce, we, out);
}

// Round 2
// 203.274 us; speedup vs baseline: 4.9665x; 4.9665x over previous
//
#include <hip/hip_runtime.h>
#include <stdint.h>

#define Bv 16
#define Sv 512
#define Hv 12
#define Dv 64
#define HIDv 768

typedef __attribute__((ext_vector_type(8))) short bf8_t;          // 8 bf16 raw
typedef __attribute__((ext_vector_type(4))) float f32x4;
typedef __attribute__((ext_vector_type(8))) unsigned short u16x8;
typedef __attribute__((ext_vector_type(4))) unsigned short u16x4;

__device__ __forceinline__ float b2f(unsigned short u){
    union { unsigned int i; float f; } x; x.i = ((unsigned int)u) << 16; return x.f;
}
__device__ __forceinline__ unsigned short f2b(float f){
    union { float f; unsigned int i; } x; x.f = f;
    unsigned int r = x.i + 0x7fff + ((x.i >> 16) & 1);   // RNE
    return (unsigned short)(r >> 16);
}

// ---------------------------------------------------------------------------
// f32 -> bf16 elementwise convert (vectorized, grid-stride)
// ---------------------------------------------------------------------------
__global__ void cvt_bf16(const float* __restrict__ src, unsigned short* __restrict__ dst, int n4){
    int i = blockIdx.x * 256 + threadIdx.x;
    int stride = gridDim.x * 256;
    for (; i < n4; i += stride){
        float4 v = ((const float4*)src)[i];
        u16x4 o = { f2b(v.x), f2b(v.y), f2b(v.z), f2b(v.w) };
        ((u16x4*)dst)[i] = o;
    }
}

// ---------------------------------------------------------------------------
// QKV projection: C[m][n] = sum_k Xb[m][k] * Wb[n][k] + bias[n]
// M=8192 (b,s), N=2304 (proj*768 + h*64 + d), K=768. BM=BN=128, BK=32.
// 4 waves in 2x2 grid, each 64x64 (4x4 frags of 16x16x32 bf16 MFMA).
// Q,K stored [proj][b][h][s][d] bf16;  V stored transposed [b][h][d][s] bf16.
// ---------------------------------------------------------------------------
__global__ __launch_bounds__(256,3) void qkv_gemm(
    const unsigned short* __restrict__ Xb,   // [8192][768]
    const unsigned short* __restrict__ Wb,   // [2304][768]
    const float* __restrict__ bq, const float* __restrict__ bk, const float* __restrict__ bv,
    unsigned short* __restrict__ qkb,        // [2][16][12][512][64]
    unsigned short* __restrict__ vtb)        // [16][12][64][512]
{
    __shared__ unsigned short Ab[128*40];    // padded stride 40 ushorts (80B)
    __shared__ unsigned short Bb[128*40];
    const int t = threadIdx.x;
    const int w = t >> 6, lane = t & 63, g = lane >> 4, cc = lane & 15;
    const int wm = w >> 1, wn = w & 1;
    const int m0 = blockIdx.x * 128;
    const int n0 = blockIdx.y * 128;

    const f32x4 fz = {0.f,0.f,0.f,0.f};
    f32x4 acc[4][4];
    #pragma unroll
    for (int i = 0; i < 4; ++i)
        #pragma unroll
        for (int j = 0; j < 4; ++j) acc[i][j] = fz;

    u16x8 pa[2], pb[2];
    #pragma unroll
    for (int r = 0; r < 2; ++r){
        int chunk = t + r*256; int row = chunk >> 2; int ch = chunk & 3;
        pa[r] = *(const u16x8*)(Xb + (size_t)(m0+row)*768 + ch*8);
        pb[r] = *(const u16x8*)(Wb + (size_t)(n0+row)*768 + ch*8);
    }
    for (int k0 = 0; k0 < 768; k0 += 32){
        __syncthreads();
        #pragma unroll
        for (int r = 0; r < 2; ++r){
            int chunk = t + r*256; int row = chunk >> 2; int ch = chunk & 3;
            *(u16x8*)&Ab[row*40 + ch*8] = pa[r];
            *(u16x8*)&Bb[row*40 + ch*8] = pb[r];
        }
        __syncthreads();
        if (k0 + 32 < 768){
            #pragma unroll
            for (int r = 0; r < 2; ++r){
                int chunk = t + r*256; int row = chunk >> 2; int ch = chunk & 3;
                pa[r] = *(const u16x8*)(Xb + (size_t)(m0+row)*768 + (k0+32) + ch*8);
                pb[r] = *(const u16x8*)(Wb + (size_t)(n0+row)*768 + (k0+32) + ch*8);
            }
        }
        bf8_t af[4], bfr[4];
        #pragma unroll
        for (int mf = 0; mf < 4; ++mf)
            af[mf] = *(const bf8_t*)&Ab[(wm*64 + mf*16 + cc)*40 + g*8];
        #pragma unroll
        for (int nf = 0; nf < 4; ++nf)
            bfr[nf] = *(const bf8_t*)&Bb[(wn*64 + nf*16 + cc)*40 + g*8];
        #pragma unroll
        for (int mf = 0; mf < 4; ++mf)
            #pragma unroll
            for (int nf = 0; nf < 4; ++nf)
                acc[mf][nf] = __builtin_amdgcn_mfma_f32_16x16x32_bf16(af[mf], bfr[nf], acc[mf][nf], 0,0,0);
    }

    const int b  = m0 >> 9;
    const int s0 = (m0 & 511) + wm*64;
    const int nbase = n0 + wn*64;
    const int proj = nbase / 768;
    const int nin0 = nbase % 768;
    const float* bias = proj == 0 ? bq : (proj == 1 ? bk : bv);
    #pragma unroll
    for (int nf = 0; nf < 4; ++nf){
        int nin = nin0 + nf*16 + cc;
        int h = nin >> 6, d = nin & 63;
        float bvv = bias[nin];
        #pragma unroll
        for (int mf = 0; mf < 4; ++mf){
            int s = s0 + mf*16 + g*4;
            if (proj < 2){
                unsigned short* base = qkb + (((((size_t)proj*Bv + b)*Hv + h)*Sv + s)*Dv + d);
                #pragma unroll
                for (int r2 = 0; r2 < 4; ++r2)
                    base[(size_t)r2*Dv] = f2b(acc[mf][nf][r2] + bvv);
            } else {
                u16x4 o = { f2b(acc[mf][nf][0]+bvv), f2b(acc[mf][nf][1]+bvv),
                            f2b(acc[mf][nf][2]+bvv), f2b(acc[mf][nf][3]+bvv) };
                *(u16x4*)(vtb + ((((size_t)b*Hv + h)*Dv + d)*Sv + s)) = o;
            }
        }
    }
}

// ---------------------------------------------------------------------------
// Fused attention. Block = (b,h,64 l-rows), 4 waves; r-chunks of 64.
// Scores = Q*K^T + gather(T1) + gather(T2) + bias, all matmuls via MFMA.
// T1 = Q * DE_band^T, T2 = K * DE_band^T  (band rows j = l-r+511).
// LDS (75.5KB): ks, vsq(Q then V), des(/P alias), t1c, t2c, bias, tab.
// ---------------------------------------------------------------------------
__global__ __launch_bounds__(256,2) void attn(
    const unsigned short* __restrict__ qkb,
    const unsigned short* __restrict__ vtb,
    const unsigned short* __restrict__ deb,   // [1023][64] bf16
    const float* __restrict__ mask,           // [16][512]
    const int*   __restrict__ cmat,
    const int*   __restrict__ wmat,
    const float* __restrict__ ce, const float* __restrict__ we,
    float* __restrict__ out)                  // [16][512][768]
{
    __shared__ __align__(16) unsigned short sm[37760];
    unsigned short* ks  = sm;            // [64][64] swizzled   (4096)
    unsigned short* vsq = sm + 4096;     // [64][64] swizzled   (4096)  Q first, then V
    unsigned short* des = sm + 8192;     // [128][64] swizzled  (8192); P alias [64][72]
    unsigned short* t1c = sm + 16384;    // [128][66]           (8448)
    unsigned short* t2c = sm + 24832;    // [128][66]           (8448)
    unsigned short* bia = sm + 33280;    // [64][68]            (4352)
    float* tab = (float*)(sm + 37632);   // 64 f32

    const int t = threadIdx.x, w = t >> 6, lane = t & 63, g = lane >> 4, cc = lane & 15;

    // XCD-bijective remap: blocks sharing (b,h) land on the same XCD
    const int wg = blockIdx.x;
    const int xcd = wg & 7, inner = wg >> 3, lt = inner & 7, gg = inner >> 3;
    const int bh = gg * 8 + xcd;              // 0..191
    const int b = bh / Hv, h = bh % Hv;
    const int l0 = lt * 64;

    const unsigned short* qp = qkb + ((((size_t)0*Bv + b)*Hv + h)*Sv + l0)*Dv;
    const unsigned short* kp = qkb + ((((size_t)1*Bv + b)*Hv + h)*Sv)*Dv;
    const unsigned short* vp = vtb + (((size_t)b*Hv + h)*Dv)*Sv;
    const int* crow = cmat + ((size_t)b*Sv + l0)*Sv;
    const int* wrow = wmat + ((size_t)b*Sv + l0)*Sv;

    if (t < 64) tab[t] = 0.5f*ce[t>>3] + 0.5f*we[t&7];

    // stage Q (swizzled) into vsq, then pull Q frags to registers (reused 8 steps)
    #pragma unroll
    for (int r = 0; r < 2; ++r){
        int chunk = t + r*256; int row = chunk >> 3, ch = chunk & 7;
        u16x8 v = *(const u16x8*)(qp + row*64 + ch*8);
        *(u16x8*)&vsq[row*64 + ((ch ^ (row & 7))*8)] = v;
    }
    __syncthreads();
    bf8_t qf[2];
    {
        int row = w*16 + cc;
        qf[0] = *(const bf8_t*)&vsq[row*64 + ((g       ^ (row & 7))*8)];
        qf[1] = *(const bf8_t*)&vsq[row*64 + (((g + 4) ^ (row & 7))*8)];
    }

    const f32x4 fz = {0.f,0.f,0.f,0.f};
    float m_run[4] = {-1e30f,-1e30f,-1e30f,-1e30f};
    float l_run[4] = {0.f,0.f,0.f,0.f};
    f32x4 ctx[4] = {fz,fz,fz,fz};
    const int llb = w*16 + g*4;

    for (int c8 = 0; c8 < 8; ++c8){
        const int r0 = c8 * 64;
        __syncthreads();                                   // B1: prev step done
        // ---- staging ----
        #pragma unroll
        for (int r = 0; r < 2; ++r){                       // K tile
            int chunk = t + r*256; int row = chunk >> 3, ch = chunk & 7;
            u16x8 v = *(const u16x8*)(kp + (size_t)(r0+row)*64 + ch*8);
            *(u16x8*)&ks[row*64 + ((ch ^ (row & 7))*8)] = v;
        }
        const int base = l0 - r0 + 448;                    // DE band, 128 rows
        #pragma unroll
        for (int r = 0; r < 4; ++r){
            int chunk = t + r*256; int row = chunk >> 3, ch = chunk & 7;
            int gr = base + row; if (gr > 1022) gr = 1022;
            u16x8 v = *(const u16x8*)(deb + (size_t)gr*64 + ch*8);
            *(u16x8*)&des[row*64 + ((ch ^ (row & 7))*8)] = v;
        }
        #pragma unroll
        for (int r = 0; r < 2; ++r){                       // V tile (src is [d][s])
            int chunk = t + r*256; int row = chunk >> 3, ch = chunk & 7;
            u16x8 v = *(const u16x8*)(vp + (size_t)row*512 + r0 + ch*8);
            *(u16x8*)&vsq[row*64 + ((ch ^ (row & 7))*8)] = v;
        }
        {   // bias tile: tab[(c<<3)|w] + 8*mask
            int ll = t >> 2, rl0 = (t & 3) * 16;
            const int* cr = crow + (size_t)ll*512 + r0 + rl0;
            const int* wr = wrow + (size_t)ll*512 + r0 + rl0;
            const float* mr = mask + b*512 + r0 + rl0;
            unsigned short* dst = &bia[ll*68 + rl0];
            #pragma unroll
            for (int q = 0; q < 4; ++q){
                int4 cv = ((const int4*)cr)[q];
                int4 wv = ((const int4*)wr)[q];
                float4 mv = ((const float4*)mr)[q];
                u16x4 o = { f2b(tab[(cv.x<<3)|wv.x] + 8.f*mv.x),
                            f2b(tab[(cv.y<<3)|wv.y] + 8.f*mv.y),
                            f2b(tab[(cv.z<<3)|wv.z] + 8.f*mv.z),
                            f2b(tab[(cv.w<<3)|wv.w] + 8.f*mv.w) };
                *(u16x4*)(dst + q*4) = o;
            }
        }
        __syncthreads();                                   // B2: tiles ready

        // ---- MFMA phase ----
        f32x4 accs[4] = {fz,fz,fz,fz};
        #pragma unroll
        for (int nf = 0; nf < 4; ++nf){                    // S = Q K^T
            int row = nf*16 + cc;
            bf8_t b0 = *(const bf8_t*)&ks[row*64 + ((g       ^ (row & 7))*8)];
            bf8_t b1 = *(const bf8_t*)&ks[row*64 + (((g + 4) ^ (row & 7))*8)];
            accs[nf] = __builtin_amdgcn_mfma_f32_16x16x32_bf16(qf[0], b0, accs[nf], 0,0,0);
            accs[nf] = __builtin_amdgcn_mfma_f32_16x16x32_bf16(qf[1], b1, accs[nf], 0,0,0);
        }
        f32x4 at1[5] = {fz,fz,fz,fz,fz};
        #pragma unroll
        for (int i = 0; i < 5; ++i){                       // T1 = Q DE^T (nf2 = w..w+4)
            int jb = (w + i)*16 + cc;
            bf8_t d0 = *(const bf8_t*)&des[jb*64 + ((g       ^ (jb & 7))*8)];
            bf8_t d1 = *(const bf8_t*)&des[jb*64 + (((g + 4) ^ (jb & 7))*8)];
            at1[i] = __builtin_amdgcn_mfma_f32_16x16x32_bf16(qf[0], d0, at1[i], 0,0,0);
            at1[i] = __builtin_amdgcn_mfma_f32_16x16x32_bf16(qf[1], d1, at1[i], 0,0,0);
        }
        bf8_t kf[2];
        {
            int row = w*16 + cc;
            kf[0] = *(const bf8_t*)&ks[row*64 + ((g       ^ (row & 7))*8)];
            kf[1] = *(const bf8_t*)&ks[row*64 + (((g + 4) ^ (row & 7))*8)];
        }
        f32x4 at2[5] = {fz,fz,fz,fz,fz};
        #pragma unroll
        for (int i = 0; i < 5; ++i){                       // T2 = K DE^T (nf2 = 3-w..7-w)
            int jb = (3 - w + i)*16 + cc;
            bf8_t d0 = *(const bf8_t*)&des[jb*64 + ((g       ^ (jb & 7))*8)];
            bf8_t d1 = *(const bf8_t*)&des[jb*64 + (((g + 4) ^ (jb & 7))*8)];
            at2[i] = __builtin_amdgcn_mfma_f32_16x16x32_bf16(kf[0], d0, at2[i], 0,0,0);
            at2[i] = __builtin_amdgcn_mfma_f32_16x16x32_bf16(kf[1], d1, at2[i], 0,0,0);
        }
        #pragma unroll
        for (int i = 0; i < 5; ++i){                       // T1 -> LDS col-major [jb][ll]
            int jb = (w + i)*16 + cc;
            unsigned int lo = (unsigned)f2b(at1[i][0]) | ((unsigned)f2b(at1[i][1]) << 16);
            unsigned int hi = (unsigned)f2b(at1[i][2]) | ((unsigned)f2b(at1[i][3]) << 16);
            *(unsigned int*)&t1c[jb*66 + llb]     = lo;
            *(unsigned int*)&t1c[jb*66 + llb + 2] = hi;
        }
        #pragma unroll
        for (int i = 0; i < 5; ++i){                       // T2 -> LDS col-major [jb][rl]
            int jb = (3 - w + i)*16 + cc;
            unsigned int lo = (unsigned)f2b(at2[i][0]) | ((unsigned)f2b(at2[i][1]) << 16);
            unsigned int hi = (unsigned)f2b(at2[i][2]) | ((unsigned)f2b(at2[i][3]) << 16);
            *(unsigned int*)&t2c[jb*66 + llb]     = lo;
            *(unsigned int*)&t2c[jb*66 + llb + 2] = hi;
        }
        __syncthreads();                                   // B3: T1/T2 visible

        // ---- epilogue: combine, online softmax, P ----
        float sv[4][4];                                    // [reg][nf]
        #pragma unroll
        for (int nf = 0; nf < 4; ++nf){
            int rl = nf*16 + cc;
            #pragma unroll
            for (int reg = 0; reg < 4; ++reg){
                int ll = llb + reg;
                int jb = ll - rl + 63;
                float t1v = b2f(t1c[jb*66 + ll]);
                float t2v = b2f(t2c[jb*66 + rl]);
                float bbv = b2f(bia[ll*68 + rl]);
                sv[reg][nf] = (accs[nf][reg] + t1v + t2v + bbv) * 0.125f;
            }
        }
        unsigned short* P = des;                           // alias: [64][72]
        #pragma unroll
        for (int reg = 0; reg < 4; ++reg){
            float rmax = fmaxf(fmaxf(sv[reg][0], sv[reg][1]), fmaxf(sv[reg][2], sv[reg][3]));
            rmax = fmaxf(rmax, __shfl_xor(rmax, 1));
            rmax = fmaxf(rmax, __shfl_xor(rmax, 2));
            rmax = fmaxf(rmax, __shfl_xor(rmax, 4));
            rmax = fmaxf(rmax, __shfl_xor(rmax, 8));
            float mnew = fmaxf(m_run[reg], rmax);
            float resc = __expf(m_run[reg] - mnew);
            float ps = 0.f;
            int ll = llb + reg;
            #pragma unroll
            for (int nf = 0; nf < 4; ++nf){
                float p = __expf(sv[reg][nf] - mnew);
                ps += p;
                P[ll*72 + nf*16 + cc] = f2b(p);
            }
            ps += __shfl_xor(ps, 1); ps += __shfl_xor(ps, 2);
            ps += __shfl_xor(ps, 4); ps += __shfl_xor(ps, 8);
            l_run[reg] = l_run[reg]*resc + ps;
            m_run[reg] = mnew;
            ctx[0][reg] *= resc; ctx[1][reg] *= resc;
            ctx[2][reg] *= resc; ctx[3][reg] *= resc;
        }

        // ---- PV (wave-local P round trip) ----
        #pragma unroll
        for (int kh = 0; kh < 2; ++kh){
            int prow = w*16 + cc;
            bf8_t pf = *(const bf8_t*)&P[prow*72 + g*8 + kh*32];
            #pragma unroll
            for (int nf = 0; nf < 4; ++nf){
                int vr = nf*16 + cc;
                bf8_t vf = *(const bf8_t*)&vsq[vr*64 + (((g + 4*kh) ^ (vr & 7))*8)];
                ctx[nf] = __builtin_amdgcn_mfma_f32_16x16x32_bf16(pf, vf, ctx[nf], 0,0,0);
            }
        }
    }

    #pragma unroll
    for (int nf = 0; nf < 4; ++nf){
        #pragma unroll
        for (int reg = 0; reg < 4; ++reg){
            int ll = llb + reg;
            out[((size_t)b*Sv + l0 + ll)*HIDv + h*64 + nf*16 + cc] = ctx[nf][reg] / l_run[reg];
        }
    }
}

extern "C" void kernel_launch(void* const* d_in, const int* in_sizes, int n_in,
                              void* d_out, int out_size, void* d_ws, size_t ws_size,
                              hipStream_t stream)
{
    const float* hs   = (const float*)d_in[0];
    const float* mask = (const float*)d_in[1];
    const int*   cmat = (const int*)  d_in[2];
    const int*   wmat = (const int*)  d_in[3];
    const float* Wq   = (const float*)d_in[4];
    const float* bq   = (const float*)d_in[5];
    const float* Wk   = (const float*)d_in[6];
    const float* bk   = (const float*)d_in[7];
    const float* Wv   = (const float*)d_in[8];
    const float* bv   = (const float*)d_in[9];
    const float* de   = (const float*)d_in[10];
    const float* ce   = (const float*)d_in[11];
    const float* we   = (const float*)d_in[12];
    float* out = (float*)d_out;

    unsigned short* Xb  = (unsigned short*)d_ws;           // 8192*768
    unsigned short* Wb  = Xb  + 6291456;                   // 2304*768
    unsigned short* deb = Wb  + 1769472;                   // 1023*64 (pad 65536)
    unsigned short* qkb = deb + 65536;                     // 2*16*12*512*64
    unsigned short* vtb = qkb + 12582912;                  // 16*12*64*512

    cvt_bf16<<<2048, 256, 0, stream>>>(hs, Xb, 1572864);
    cvt_bf16<<<512,  256, 0, stream>>>(Wq, Wb,            147456);
    cvt_bf16<<<512,  256, 0, stream>>>(Wk, Wb + 589824,   147456);
    cvt_bf16<<<512,  256, 0, stream>>>(Wv, Wb + 1179648,  147456);
    cvt_bf16<<<64,   256, 0, stream>>>(de, deb, 16368);

    qkv_gemm<<<dim3(64, 18), 256, 0, stream>>>(Xb, Wb, bq, bk, bv, qkb, vtb);
    attn<<<1536, 256, 0, stream>>>(qkb, vtb, deb, mask, cmat, wmat, ce, we, out);
}